// Round 13
// baseline (104.508 us; speedup 1.0000x reference)
//
#include <hip/hip_runtime.h>

typedef float f32x4 __attribute__((ext_vector_type(4)));
typedef short bf16x8 __attribute__((ext_vector_type(8)));

#define HW_ 1024
#define NE_ 4096
#define CHW_ 65536          // 64*1024
#define ZQ_SIZE 1048576
#define LOSS_OFF ZQ_SIZE
#define IDX_OFF (ZQ_SIZE + 1)
#define LOSS_SCALE (1.25f / 1048576.f)
#define EPS_GAP 0.1f        // 0.5*d2 scale; covers 12-bit trunc + split err (~1e-5)

union FragU { unsigned u[4]; bf16x8 v; };

__device__ __forceinline__ unsigned umin_(unsigned a, unsigned b) { return a < b ? a : b; }
__device__ __forceinline__ unsigned umax_(unsigned a, unsigned b) { return a > b ? a : b; }

// split 8 f32 -> hi/lo bf16 fragments (truncation split; lo captures the tail)
__device__ __forceinline__ void split8(const float* v, FragU& hi, FragU& lo) {
#pragma unroll
    for (int p = 0; p < 4; p++) {
        float a = v[2 * p], b = v[2 * p + 1];
        unsigned ua = __float_as_uint(a), ub = __float_as_uint(b);
        hi.u[p] = (ua >> 16) | (ub & 0xFFFF0000u);
        float la = a - __uint_as_float(ua & 0xFFFF0000u);
        float lb = b - __uint_as_float(ub & 0xFFFF0000u);
        lo.u[p] = (__float_as_uint(la) >> 16) | (__float_as_uint(lb) & 0xFFFF0000u);
    }
}

__device__ __forceinline__ void gload_lds16(const void* g, void* l) {
    __builtin_amdgcn_global_load_lds(
        (const __attribute__((address_space(1))) unsigned*)g,
        (__attribute__((address_space(3))) unsigned*)l, 16, 0, 0);
}

// ---- kernel 1: efrag (negated, split) + h_e + cnt/loss init --------------
__global__ __launch_bounds__(256) void vq_eprep(
        const float* __restrict__ emb, char* __restrict__ efrag,
        float* __restrict__ h_e, unsigned* __restrict__ cnt,
        float* __restrict__ out) {
    const int bid = blockIdx.x, tid = threadIdx.x;
    if (bid < 128) {                       // e fragments, negated (4 KB/tile)
        int u = bid * 256 + tid;
        int l = u & 63, s = (u >> 6) & 1, t = u >> 7;   // t 0..255
        int er = t * 16 + (l & 15);
        int c0 = s * 32 + (l >> 4) * 8;
        const float* ep = emb + (size_t)er * 64 + c0;
        float4 ea = *(const float4*)(ep);
        float4 eb = *(const float4*)(ep + 4);
        float v[8];
        v[0] = -ea.x; v[1] = -ea.y; v[2] = -ea.z; v[3] = -ea.w;
        v[4] = -eb.x; v[5] = -eb.y; v[6] = -eb.z; v[7] = -eb.w;
        FragU hi, lo;
        split8(v, hi, lo);
        char* base = efrag + (size_t)t * 4096 + l * 16;
        *(FragU*)(base + s * 1024) = hi;
        *(FragU*)(base + (2 + s) * 1024) = lo;
    } else if (bid < 144) {                // h_e (16 blocks)
        int t = (bid - 128) * 256 + tid;   // 0..4095
        const float4* er = (const float4*)(emb + (size_t)t * 64);
        float s = 0.f;
#pragma unroll
        for (int k = 0; k < 16; k++) {
            float4 e4 = er[k];
            s = fmaf(e4.x, e4.x, s); s = fmaf(e4.y, e4.y, s);
            s = fmaf(e4.z, e4.z, s); s = fmaf(e4.w, e4.w, s);
        }
        h_e[t] = 0.5f * s;
    } else {                               // cnt zero + loss zero
        if (tid < 32) cnt[tid] = 0;
        if (tid == 32) out[LOSS_OFF] = 0.f;
    }
}

// ---- kernel 2: fused MFMA scan + last-block epilogue ---------------------
// Grid 256 = 32 row-blocks x 8 e-splits -> 1 block/CU. Block = 8 waves.
// Entry: build z-frags in registers from z (strided loads + split), h_z via
// shfl. Scan: R12's loop (e staged via global_load_lds, 8-wave reuse,
// 5 ds_read -> 24 MFMA per e-tile). Tail: partial top-2 stores; the LAST
// block per row-group (device atomic) merges 8 partials, fp64-duels
// near-ties, writes idx / z_q / loss.
__global__ __launch_bounds__(512) void vq_mfma(
        const float* __restrict__ z, const float* __restrict__ emb,
        const char* __restrict__ efrag, const float* __restrict__ h_e,
        unsigned* __restrict__ k1q, unsigned* __restrict__ k2q,
        unsigned* __restrict__ cnt, float* __restrict__ out) {
    __shared__ char buf[2][32768];
    __shared__ __attribute__((aligned(16))) float sh_he[512];
    __shared__ int s_last;

    const int tid = threadIdx.x;
    const int lane = tid & 63;
    const int w = tid >> 6;
    const int lrow = lane & 15;
    const int lgrp = lane >> 4;
    const int es = blockIdx.x & 7;    // e-split (512 e = 32 et)
    const int rb = blockIdx.x >> 3;   // row-group (512 rows)
    const int e0t = es * 32;
    const int rt0 = rb * 32 + w * 4;  // wave's four row-tiles
    const int b = rb >> 1;            // batch image (block never crosses)

    sh_he[tid] = h_e[es * 512 + tid];

    // stage chunk 0: wave w stages e-tile (e0t + w)
    {
        const char* src = efrag + (size_t)(e0t + w) * 4096 + lane * 16;
        char* dst = buf[0] + w * 4096;
#pragma unroll
        for (int i = 0; i < 4; i++) gload_lds16(src + i * 1024, dst + i * 1024);
    }

    // build z-frags in registers (4 row-tiles x hi/lo x 2 k-halves) + norms
    bf16x8 zh[4][2], zl[4][2];
    float hz[4];
#pragma unroll
    for (int r = 0; r < 4; r++) {
        float ss = 0.f;
#pragma unroll
        for (int s = 0; s < 2; s++) {
            const int hw = ((rt0 + r) * 16 + lrow) & 1023;
            const int c0 = s * 32 + lgrp * 8;
            const float* zp = z + (size_t)b * CHW_ + hw;
            float v[8];
#pragma unroll
            for (int j = 0; j < 8; j++) {
                v[j] = zp[(c0 + j) * HW_];
                ss = fmaf(v[j], v[j], ss);
            }
            FragU hi, lo;
            split8(v, hi, lo);
            zh[r][s] = hi.v;
            zl[r][s] = lo.v;
        }
        ss += __shfl_xor(ss, 16);      // butterfly over lgrp (lane bits 4,5)
        ss += __shfl_xor(ss, 32);
        hz[r] = 0.5f * ss;
    }

    unsigned s1k[4] = {~0u, ~0u, ~0u, ~0u};
    unsigned s2k[4] = {~0u, ~0u, ~0u, ~0u};

    __syncthreads();                  // chunk 0 staged (barrier drains vmcnt)
    for (int c = 0; c < 4; c++) {
        if (c < 3) {                  // issue next-chunk stage early
            const char* src = efrag + (size_t)(e0t + (c + 1) * 8 + w) * 4096
                              + lane * 16;
            char* dst = buf[(c + 1) & 1] + w * 4096;
#pragma unroll
            for (int i = 0; i < 4; i++) gload_lds16(src + i * 1024, dst + i * 1024);
        }

        const char* cb = buf[c & 1] + lane * 16;
#pragma unroll
        for (int j = 0; j < 8; j++) {
            const char* tb = cb + j * 4096;
            bf16x8 ah0 = *(const bf16x8*)(tb);
            bf16x8 ah1 = *(const bf16x8*)(tb + 1024);
            bf16x8 al0 = *(const bf16x8*)(tb + 2048);
            bf16x8 al1 = *(const bf16x8*)(tb + 3072);
            const int etl = c * 8 + j;
            const f32x4 he = *(const f32x4*)&sh_he[etl * 16 + lgrp * 4];

            f32x4 a0 = he + hz[0], a1 = he + hz[1];
            f32x4 a2 = he + hz[2], a3 = he + hz[3];

            a0 = __builtin_amdgcn_mfma_f32_16x16x32_bf16(ah0, zh[0][0], a0, 0, 0, 0);
            a1 = __builtin_amdgcn_mfma_f32_16x16x32_bf16(ah0, zh[1][0], a1, 0, 0, 0);
            a2 = __builtin_amdgcn_mfma_f32_16x16x32_bf16(ah0, zh[2][0], a2, 0, 0, 0);
            a3 = __builtin_amdgcn_mfma_f32_16x16x32_bf16(ah0, zh[3][0], a3, 0, 0, 0);
            a0 = __builtin_amdgcn_mfma_f32_16x16x32_bf16(ah1, zh[0][1], a0, 0, 0, 0);
            a1 = __builtin_amdgcn_mfma_f32_16x16x32_bf16(ah1, zh[1][1], a1, 0, 0, 0);
            a2 = __builtin_amdgcn_mfma_f32_16x16x32_bf16(ah1, zh[2][1], a2, 0, 0, 0);
            a3 = __builtin_amdgcn_mfma_f32_16x16x32_bf16(ah1, zh[3][1], a3, 0, 0, 0);
            a0 = __builtin_amdgcn_mfma_f32_16x16x32_bf16(al0, zh[0][0], a0, 0, 0, 0);
            a1 = __builtin_amdgcn_mfma_f32_16x16x32_bf16(al0, zh[1][0], a1, 0, 0, 0);
            a2 = __builtin_amdgcn_mfma_f32_16x16x32_bf16(al0, zh[2][0], a2, 0, 0, 0);
            a3 = __builtin_amdgcn_mfma_f32_16x16x32_bf16(al0, zh[3][0], a3, 0, 0, 0);
            a0 = __builtin_amdgcn_mfma_f32_16x16x32_bf16(al1, zh[0][1], a0, 0, 0, 0);
            a1 = __builtin_amdgcn_mfma_f32_16x16x32_bf16(al1, zh[1][1], a1, 0, 0, 0);
            a2 = __builtin_amdgcn_mfma_f32_16x16x32_bf16(al1, zh[2][1], a2, 0, 0, 0);
            a3 = __builtin_amdgcn_mfma_f32_16x16x32_bf16(al1, zh[3][1], a3, 0, 0, 0);
            a0 = __builtin_amdgcn_mfma_f32_16x16x32_bf16(ah0, zl[0][0], a0, 0, 0, 0);
            a1 = __builtin_amdgcn_mfma_f32_16x16x32_bf16(ah0, zl[1][0], a1, 0, 0, 0);
            a2 = __builtin_amdgcn_mfma_f32_16x16x32_bf16(ah0, zl[2][0], a2, 0, 0, 0);
            a3 = __builtin_amdgcn_mfma_f32_16x16x32_bf16(ah0, zl[3][0], a3, 0, 0, 0);
            a0 = __builtin_amdgcn_mfma_f32_16x16x32_bf16(ah1, zl[0][1], a0, 0, 0, 0);
            a1 = __builtin_amdgcn_mfma_f32_16x16x32_bf16(ah1, zl[1][1], a1, 0, 0, 0);
            a2 = __builtin_amdgcn_mfma_f32_16x16x32_bf16(ah1, zl[2][1], a2, 0, 0, 0);
            a3 = __builtin_amdgcn_mfma_f32_16x16x32_bf16(ah1, zl[3][1], a3, 0, 0, 0);

            const unsigned eb12 = (unsigned)(es * 512 + etl * 16 + lgrp * 4);
#pragma unroll
            for (int rr = 0; rr < 4; rr++) {
                unsigned key0 = (__float_as_uint(a0[rr]) & 0xFFFFF000u) | (eb12 + rr);
                s2k[0] = umin_(s2k[0], umax_(s1k[0], key0));
                s1k[0] = umin_(s1k[0], key0);
                unsigned key1 = (__float_as_uint(a1[rr]) & 0xFFFFF000u) | (eb12 + rr);
                s2k[1] = umin_(s2k[1], umax_(s1k[1], key1));
                s1k[1] = umin_(s1k[1], key1);
                unsigned key2 = (__float_as_uint(a2[rr]) & 0xFFFFF000u) | (eb12 + rr);
                s2k[2] = umin_(s2k[2], umax_(s1k[2], key2));
                s1k[2] = umin_(s1k[2], key2);
                unsigned key3 = (__float_as_uint(a3[rr]) & 0xFFFFF000u) | (eb12 + rr);
                s2k[3] = umin_(s2k[3], umax_(s1k[3], key3));
                s1k[3] = umin_(s1k[3], key3);
            }
        }
        __syncthreads();              // next chunk landed; buf[c&1] free
    }

    // merge across the 4 k-octet lane-groups (same z-row)
#pragma unroll
    for (int off = 16; off <= 32; off += 16) {
#pragma unroll
        for (int r = 0; r < 4; r++) {
            unsigned o1 = (unsigned)__shfl_xor((int)s1k[r], off);
            unsigned o2 = (unsigned)__shfl_xor((int)s2k[r], off);
            s2k[r] = umin_(umin_(s2k[r], o2), umax_(s1k[r], o1));
            s1k[r] = umin_(s1k[r], o1);
        }
    }

    if (lane < 16) {                  // partial stores; one owner per (row, es)
        const int base = es * 16384;
#pragma unroll
        for (int r = 0; r < 4; r++) {
            k1q[base + (rt0 + r) * 16 + lane] = s1k[r];
            k2q[base + (rt0 + r) * 16 + lane] = s2k[r];
        }
    }

    // ---- publish partials; last block of this row-group runs epilogue ----
    __threadfence();                  // release: partials visible device-wide
    __syncthreads();
    if (tid == 0) s_last = (atomicAdd(&cnt[rb], 1u) == 7u);
    __syncthreads();
    if (!s_last) return;
    __threadfence();                  // acquire: other blocks' partials

    {
        const int n = rb * 512 + tid;          // this thread's row
        unsigned m = ~0u, s = ~0u;
#pragma unroll
        for (int i = 0; i < 8; i++) {
            unsigned a = k1q[i * 16384 + n];
            unsigned bb = k2q[i * 16384 + n];
            unsigned hi = umax_(m, a);
            m = umin_(m, a);
            s = umin_(umin_(s, bb), hi);
        }
        int idx = (int)(m & 0xFFFu);
        float sc1 = __uint_as_float(m & 0xFFFFF000u);
        float sc2 = __uint_as_float(s & 0xFFFFF000u);

        const int hw = n & 1023;
        const float* zp = z + (size_t)b * CHW_ + hw;

        if (sc2 - sc1 < EPS_GAP) {             // rare: exact fp64 duel
            int i2 = (int)(s & 0xFFFu);
            const float* ea = emb + (size_t)idx * 64;
            const float* eb2 = emb + (size_t)i2 * 64;
            double da = 0.0, db = 0.0;
#pragma unroll 8
            for (int c = 0; c < 64; c++) {
                double zv = (double)zp[c * HW_];
                double xa = (double)ea[c] - zv;
                double xb = (double)eb2[c] - zv;
                da = fma(xa, xa, da);
                db = fma(xb, xb, db);
            }
            if (db < da || (db == da && i2 < idx)) idx = i2;
        }
        out[IDX_OFF + n] = (float)idx;

        const float* er = emb + (size_t)idx * 64;
        float* zq = out + (size_t)b * CHW_ + hw;
        float lsum = 0.f;
#pragma unroll
        for (int c = 0; c < 64; c++) {
            float e = er[c];
            float d = e - zp[c * HW_];
            zq[c * HW_] = e;
            lsum = fmaf(d, d, lsum);
        }
#pragma unroll
        for (int off = 32; off; off >>= 1) lsum += __shfl_down(lsum, off);
        if (lane == 0) atomicAdd(&out[LOSS_OFF], lsum * LOSS_SCALE);
    }
}

extern "C" void kernel_launch(void* const* d_in, const int* in_sizes, int n_in,
                              void* d_out, int out_size, void* d_ws, size_t ws_size,
                              hipStream_t stream) {
    const float* z   = (const float*)d_in[0];
    const float* emb = (const float*)d_in[1];
    float* out = (float*)d_out;
    char* ws = (char*)d_ws;

    char* efrag   = ws;                               // 1 MB
    float* h_e    = (float*)(ws + 1048576);           // 16 KB
    unsigned* k1q = (unsigned*)(ws + 1065024);        // 512 KB (8 partials)
    unsigned* k2q = (unsigned*)(ws + 1589312);        // 512 KB
    unsigned* cnt = (unsigned*)(ws + 2113600);        // 128 B

    vq_eprep<<<145, 256, 0, stream>>>(emb, efrag, h_e, cnt, out);
    vq_mfma <<<256, 512, 0, stream>>>(z, emb, efrag, h_e, k1q, k2q, cnt, out);
}

// Round 14
// 104.184 us; speedup vs baseline: 1.0031x; 1.0031x over previous
//
#include <hip/hip_runtime.h>

typedef float f32x4 __attribute__((ext_vector_type(4)));
typedef short bf16x8 __attribute__((ext_vector_type(8)));

#define HW_ 1024
#define NE_ 4096
#define CHW_ 65536          // 64*1024
#define ZQ_SIZE 1048576
#define LOSS_OFF ZQ_SIZE
#define IDX_OFF (ZQ_SIZE + 1)
#define LOSS_SCALE (1.25f / 1048576.f)
#define EPS_GAP 0.1f        // 0.5*d2 scale; covers 12-bit trunc + split err (~1e-5)

union FragU { unsigned u[4]; bf16x8 v; };

__device__ __forceinline__ unsigned umin_(unsigned a, unsigned b) { return a < b ? a : b; }
__device__ __forceinline__ unsigned umax_(unsigned a, unsigned b) { return a > b ? a : b; }

// split 8 f32 -> hi/lo bf16 fragments (truncation split; lo captures the tail)
__device__ __forceinline__ void split8(const float* v, FragU& hi, FragU& lo) {
#pragma unroll
    for (int p = 0; p < 4; p++) {
        float a = v[2 * p], b = v[2 * p + 1];
        unsigned ua = __float_as_uint(a), ub = __float_as_uint(b);
        hi.u[p] = (ua >> 16) | (ub & 0xFFFF0000u);
        float la = a - __uint_as_float(ua & 0xFFFF0000u);
        float lb = b - __uint_as_float(ub & 0xFFFF0000u);
        lo.u[p] = (__float_as_uint(la) >> 16) | (__float_as_uint(lb) & 0xFFFF0000u);
    }
}

__device__ __forceinline__ void gload_lds16(const void* g, void* l) {
    __builtin_amdgcn_global_load_lds(
        (const __attribute__((address_space(1))) unsigned*)g,
        (__attribute__((address_space(3))) unsigned*)l, 16, 0, 0);
}

// ---- kernel 1: efrag (negated, split) + h_e + cnt/loss init --------------
__global__ __launch_bounds__(256) void vq_eprep(
        const float* __restrict__ emb, char* __restrict__ efrag,
        float* __restrict__ h_e, unsigned* __restrict__ cnt,
        float* __restrict__ out) {
    const int bid = blockIdx.x, tid = threadIdx.x;
    if (bid < 128) {                       // e fragments, negated (4 KB/tile)
        int u = bid * 256 + tid;
        int l = u & 63, s = (u >> 6) & 1, t = u >> 7;   // t 0..255
        int er = t * 16 + (l & 15);
        int c0 = s * 32 + (l >> 4) * 8;
        const float* ep = emb + (size_t)er * 64 + c0;
        float4 ea = *(const float4*)(ep);
        float4 eb = *(const float4*)(ep + 4);
        float v[8];
        v[0] = -ea.x; v[1] = -ea.y; v[2] = -ea.z; v[3] = -ea.w;
        v[4] = -eb.x; v[5] = -eb.y; v[6] = -eb.z; v[7] = -eb.w;
        FragU hi, lo;
        split8(v, hi, lo);
        char* base = efrag + (size_t)t * 4096 + l * 16;
        *(FragU*)(base + s * 1024) = hi;
        *(FragU*)(base + (2 + s) * 1024) = lo;
    } else if (bid < 144) {                // h_e (16 blocks)
        int t = (bid - 128) * 256 + tid;   // 0..4095
        const float4* er = (const float4*)(emb + (size_t)t * 64);
        float s = 0.f;
#pragma unroll
        for (int k = 0; k < 16; k++) {
            float4 e4 = er[k];
            s = fmaf(e4.x, e4.x, s); s = fmaf(e4.y, e4.y, s);
            s = fmaf(e4.z, e4.z, s); s = fmaf(e4.w, e4.w, s);
        }
        h_e[t] = 0.5f * s;
    } else {                               // cnt zero + loss zero
        if (tid < 32) cnt[tid] = 0;
        if (tid == 32) out[LOSS_OFF] = 0.f;
    }
}

// ---- kernel 2: fused MFMA scan + last-block epilogue ---------------------
// Grid 256 = 32 row-groups x 8 e-splits -> 1 block/CU. Block = 8 waves.
// __launch_bounds__(512, 1): 1 wave/EU floor -> full VGPR budget, no spill
// (R13 lesson: default heuristic picked 84 VGPR vs ~150 demand -> spill).
__global__ __launch_bounds__(512, 1) void vq_mfma(
        const float* __restrict__ z, const float* __restrict__ emb,
        const char* __restrict__ efrag, const float* __restrict__ h_e,
        unsigned* __restrict__ k1q, unsigned* __restrict__ k2q,
        unsigned* __restrict__ cnt, float* __restrict__ out) {
    __shared__ char buf[2][32768];
    __shared__ __attribute__((aligned(16))) float sh_he[512];
    __shared__ int s_last;

    const int tid = threadIdx.x;
    const int lane = tid & 63;
    const int w = tid >> 6;
    const int lrow = lane & 15;
    const int lgrp = lane >> 4;
    const int es = blockIdx.x & 7;    // e-split (512 e = 32 et)
    const int rb = blockIdx.x >> 3;   // row-group (512 rows)
    const int e0t = es * 32;
    const int rt0 = rb * 32 + w * 4;  // wave's four row-tiles
    const int b = rb >> 1;            // batch image (block never crosses)

    sh_he[tid] = h_e[es * 512 + tid];

    // stage chunk 0: wave w stages e-tile (e0t + w)
    {
        const char* src = efrag + (size_t)(e0t + w) * 4096 + lane * 16;
        char* dst = buf[0] + w * 4096;
#pragma unroll
        for (int i = 0; i < 4; i++) gload_lds16(src + i * 1024, dst + i * 1024);
    }

    // build z-frags in registers (4 row-tiles x hi/lo x 2 k-halves) + norms
    bf16x8 zh[4][2], zl[4][2];
    float hz[4];
#pragma unroll
    for (int r = 0; r < 4; r++) {
        float ss = 0.f;
#pragma unroll
        for (int s = 0; s < 2; s++) {
            const int hw = ((rt0 + r) * 16 + lrow) & 1023;
            const int c0 = s * 32 + lgrp * 8;
            const float* zp = z + (size_t)b * CHW_ + hw;
            float v[8];
#pragma unroll
            for (int j = 0; j < 8; j++) {
                v[j] = zp[(c0 + j) * HW_];
                ss = fmaf(v[j], v[j], ss);
            }
            FragU hi, lo;
            split8(v, hi, lo);
            zh[r][s] = hi.v;
            zl[r][s] = lo.v;
        }
        ss += __shfl_xor(ss, 16);      // butterfly over lgrp (lane bits 4,5)
        ss += __shfl_xor(ss, 32);
        hz[r] = 0.5f * ss;
    }

    unsigned s1k[4] = {~0u, ~0u, ~0u, ~0u};
    unsigned s2k[4] = {~0u, ~0u, ~0u, ~0u};

    __syncthreads();                  // chunk 0 staged (barrier drains vmcnt)
    for (int c = 0; c < 4; c++) {
        if (c < 3) {                  // issue next-chunk stage early
            const char* src = efrag + (size_t)(e0t + (c + 1) * 8 + w) * 4096
                              + lane * 16;
            char* dst = buf[(c + 1) & 1] + w * 4096;
#pragma unroll
            for (int i = 0; i < 4; i++) gload_lds16(src + i * 1024, dst + i * 1024);
        }

        const char* cb = buf[c & 1] + lane * 16;
#pragma unroll
        for (int j = 0; j < 8; j++) {
            const char* tb = cb + j * 4096;
            bf16x8 ah0 = *(const bf16x8*)(tb);
            bf16x8 ah1 = *(const bf16x8*)(tb + 1024);
            bf16x8 al0 = *(const bf16x8*)(tb + 2048);
            bf16x8 al1 = *(const bf16x8*)(tb + 3072);
            const int etl = c * 8 + j;
            const f32x4 he = *(const f32x4*)&sh_he[etl * 16 + lgrp * 4];

            f32x4 a0 = he + hz[0], a1 = he + hz[1];
            f32x4 a2 = he + hz[2], a3 = he + hz[3];

            a0 = __builtin_amdgcn_mfma_f32_16x16x32_bf16(ah0, zh[0][0], a0, 0, 0, 0);
            a1 = __builtin_amdgcn_mfma_f32_16x16x32_bf16(ah0, zh[1][0], a1, 0, 0, 0);
            a2 = __builtin_amdgcn_mfma_f32_16x16x32_bf16(ah0, zh[2][0], a2, 0, 0, 0);
            a3 = __builtin_amdgcn_mfma_f32_16x16x32_bf16(ah0, zh[3][0], a3, 0, 0, 0);
            a0 = __builtin_amdgcn_mfma_f32_16x16x32_bf16(ah1, zh[0][1], a0, 0, 0, 0);
            a1 = __builtin_amdgcn_mfma_f32_16x16x32_bf16(ah1, zh[1][1], a1, 0, 0, 0);
            a2 = __builtin_amdgcn_mfma_f32_16x16x32_bf16(ah1, zh[2][1], a2, 0, 0, 0);
            a3 = __builtin_amdgcn_mfma_f32_16x16x32_bf16(ah1, zh[3][1], a3, 0, 0, 0);
            a0 = __builtin_amdgcn_mfma_f32_16x16x32_bf16(al0, zh[0][0], a0, 0, 0, 0);
            a1 = __builtin_amdgcn_mfma_f32_16x16x32_bf16(al0, zh[1][0], a1, 0, 0, 0);
            a2 = __builtin_amdgcn_mfma_f32_16x16x32_bf16(al0, zh[2][0], a2, 0, 0, 0);
            a3 = __builtin_amdgcn_mfma_f32_16x16x32_bf16(al0, zh[3][0], a3, 0, 0, 0);
            a0 = __builtin_amdgcn_mfma_f32_16x16x32_bf16(al1, zh[0][1], a0, 0, 0, 0);
            a1 = __builtin_amdgcn_mfma_f32_16x16x32_bf16(al1, zh[1][1], a1, 0, 0, 0);
            a2 = __builtin_amdgcn_mfma_f32_16x16x32_bf16(al1, zh[2][1], a2, 0, 0, 0);
            a3 = __builtin_amdgcn_mfma_f32_16x16x32_bf16(al1, zh[3][1], a3, 0, 0, 0);
            a0 = __builtin_amdgcn_mfma_f32_16x16x32_bf16(ah0, zl[0][0], a0, 0, 0, 0);
            a1 = __builtin_amdgcn_mfma_f32_16x16x32_bf16(ah0, zl[1][0], a1, 0, 0, 0);
            a2 = __builtin_amdgcn_mfma_f32_16x16x32_bf16(ah0, zl[2][0], a2, 0, 0, 0);
            a3 = __builtin_amdgcn_mfma_f32_16x16x32_bf16(ah0, zl[3][0], a3, 0, 0, 0);
            a0 = __builtin_amdgcn_mfma_f32_16x16x32_bf16(ah1, zl[0][1], a0, 0, 0, 0);
            a1 = __builtin_amdgcn_mfma_f32_16x16x32_bf16(ah1, zl[1][1], a1, 0, 0, 0);
            a2 = __builtin_amdgcn_mfma_f32_16x16x32_bf16(ah1, zl[2][1], a2, 0, 0, 0);
            a3 = __builtin_amdgcn_mfma_f32_16x16x32_bf16(ah1, zl[3][1], a3, 0, 0, 0);

            const unsigned eb12 = (unsigned)(es * 512 + etl * 16 + lgrp * 4);
#pragma unroll
            for (int rr = 0; rr < 4; rr++) {
                unsigned key0 = (__float_as_uint(a0[rr]) & 0xFFFFF000u) | (eb12 + rr);
                s2k[0] = umin_(s2k[0], umax_(s1k[0], key0));
                s1k[0] = umin_(s1k[0], key0);
                unsigned key1 = (__float_as_uint(a1[rr]) & 0xFFFFF000u) | (eb12 + rr);
                s2k[1] = umin_(s2k[1], umax_(s1k[1], key1));
                s1k[1] = umin_(s1k[1], key1);
                unsigned key2 = (__float_as_uint(a2[rr]) & 0xFFFFF000u) | (eb12 + rr);
                s2k[2] = umin_(s2k[2], umax_(s1k[2], key2));
                s1k[2] = umin_(s1k[2], key2);
                unsigned key3 = (__float_as_uint(a3[rr]) & 0xFFFFF000u) | (eb12 + rr);
                s2k[3] = umin_(s2k[3], umax_(s1k[3], key3));
                s1k[3] = umin_(s1k[3], key3);
            }
        }
        __syncthreads();              // next chunk landed; buf[c&1] free
    }

    // merge across the 4 k-octet lane-groups (same z-row)
#pragma unroll
    for (int off = 16; off <= 32; off += 16) {
#pragma unroll
        for (int r = 0; r < 4; r++) {
            unsigned o1 = (unsigned)__shfl_xor((int)s1k[r], off);
            unsigned o2 = (unsigned)__shfl_xor((int)s2k[r], off);
            s2k[r] = umin_(umin_(s2k[r], o2), umax_(s1k[r], o1));
            s1k[r] = umin_(s1k[r], o1);
        }
    }

    if (lane < 16) {                  // partial stores; one owner per (row, es)
        const int base = es * 16384;
#pragma unroll
        for (int r = 0; r < 4; r++) {
            k1q[base + (rt0 + r) * 16 + lane] = s1k[r];
            k2q[base + (rt0 + r) * 16 + lane] = s2k[r];
        }
    }

    // ---- publish partials; last block of this row-group runs epilogue ----
    __threadfence();                  // release: partials visible device-wide
    __syncthreads();
    if (tid == 0) s_last = (atomicAdd(&cnt[rb], 1u) == 7u);
    __syncthreads();
    if (!s_last) return;
    __threadfence();                  // acquire: other blocks' partials

    {
        const int n = rb * 512 + tid;          // this thread's row
        unsigned m = ~0u, s = ~0u;
#pragma unroll
        for (int i = 0; i < 8; i++) {
            unsigned a = k1q[i * 16384 + n];
            unsigned bb = k2q[i * 16384 + n];
            unsigned hi = umax_(m, a);
            m = umin_(m, a);
            s = umin_(umin_(s, bb), hi);
        }
        int idx = (int)(m & 0xFFFu);
        float sc1 = __uint_as_float(m & 0xFFFFF000u);
        float sc2 = __uint_as_float(s & 0xFFFFF000u);

        const int hw = n & 1023;
        const float* zp = z + (size_t)b * CHW_ + hw;

        if (sc2 - sc1 < EPS_GAP) {             // rare: exact fp64 duel
            int i2 = (int)(s & 0xFFFu);
            const float* ea = emb + (size_t)idx * 64;
            const float* eb2 = emb + (size_t)i2 * 64;
            double da = 0.0, db = 0.0;
#pragma unroll 8
            for (int c = 0; c < 64; c++) {
                double zv = (double)zp[c * HW_];
                double xa = (double)ea[c] - zv;
                double xb = (double)eb2[c] - zv;
                da = fma(xa, xa, da);
                db = fma(xb, xb, db);
            }
            if (db < da || (db == da && i2 < idx)) idx = i2;
        }
        out[IDX_OFF + n] = (float)idx;

        const float* er = emb + (size_t)idx * 64;
        float* zq = out + (size_t)b * CHW_ + hw;
        float lsum = 0.f;
#pragma unroll
        for (int c = 0; c < 64; c++) {
            float e = er[c];
            float d = e - zp[c * HW_];
            zq[c * HW_] = e;
            lsum = fmaf(d, d, lsum);
        }
#pragma unroll
        for (int off = 32; off; off >>= 1) lsum += __shfl_down(lsum, off);
        if (lane == 0) atomicAdd(&out[LOSS_OFF], lsum * LOSS_SCALE);
    }
}

extern "C" void kernel_launch(void* const* d_in, const int* in_sizes, int n_in,
                              void* d_out, int out_size, void* d_ws, size_t ws_size,
                              hipStream_t stream) {
    const float* z   = (const float*)d_in[0];
    const float* emb = (const float*)d_in[1];
    float* out = (float*)d_out;
    char* ws = (char*)d_ws;

    char* efrag   = ws;                               // 1 MB
    float* h_e    = (float*)(ws + 1048576);           // 16 KB
    unsigned* k1q = (unsigned*)(ws + 1065024);        // 512 KB (8 partials)
    unsigned* k2q = (unsigned*)(ws + 1589312);        // 512 KB
    unsigned* cnt = (unsigned*)(ws + 2113600);        // 128 B

    vq_eprep<<<145, 256, 0, stream>>>(emb, efrag, h_e, cnt, out);
    vq_mfma <<<256, 512, 0, stream>>>(z, emb, efrag, h_e, k1q, k2q, cnt, out);
}

// Round 16
// 51.558 us; speedup vs baseline: 2.0270x; 2.0207x over previous
//
#include <hip/hip_runtime.h>

typedef float f32x4 __attribute__((ext_vector_type(4)));
typedef short bf16x8 __attribute__((ext_vector_type(8)));

#define HW_ 1024
#define NE_ 4096
#define CHW_ 65536          // 64*1024
#define ZQ_SIZE 1048576
#define LOSS_OFF ZQ_SIZE
#define IDX_OFF (ZQ_SIZE + 1)
#define LOSS_SCALE (1.25f / 1048576.f)
#define EPS_GAP 0.1f        // 0.5*d2 scale; covers 12-bit trunc (~0.016) + split err (~1e-5)

union FragU { unsigned u[4]; bf16x8 v; };

__device__ __forceinline__ unsigned umin_(unsigned a, unsigned b) { return a < b ? a : b; }
__device__ __forceinline__ unsigned umax_(unsigned a, unsigned b) { return a > b ? a : b; }

// running top-2 update: s2 = median(key, s1, s2) ; s1 = min(s1, key)
__device__ __forceinline__ void top2_(unsigned key, unsigned& s1, unsigned& s2) {
    unsigned t;
    asm("v_med3_u32 %0, %1, %2, %3" : "=v"(t) : "v"(key), "v"(s1), "v"(s2));
    s2 = t;
    s1 = umin_(s1, key);
}

// split 8 f32 -> hi/lo bf16 fragments (truncation split; lo captures the tail)
__device__ __forceinline__ void split8(const float* v, FragU& hi, FragU& lo) {
#pragma unroll
    for (int p = 0; p < 4; p++) {
        float a = v[2 * p], b = v[2 * p + 1];
        unsigned ua = __float_as_uint(a), ub = __float_as_uint(b);
        hi.u[p] = (ua >> 16) | (ub & 0xFFFF0000u);
        float la = a - __uint_as_float(ua & 0xFFFF0000u);
        float lb = b - __uint_as_float(ub & 0xFFFF0000u);
        lo.u[p] = (__float_as_uint(la) >> 16) | (__float_as_uint(lb) & 0xFFFF0000u);
    }
}

__device__ __forceinline__ void gload_lds16(const void* g, void* l) {
    __builtin_amdgcn_global_load_lds(
        (const __attribute__((address_space(1))) unsigned*)g,
        (__attribute__((address_space(3))) unsigned*)l, 16, 0, 0);
}

// ---- kernel 1 (fused pre): z split + h_z | e split | h_e -----------------
// blocks [0,512): zfrag hi+lo + h_z; [512,640): efrag (negated); [640,656): h_e.
__global__ __launch_bounds__(256) void vq_pre(
        const float* __restrict__ z, const float* __restrict__ emb,
        float* __restrict__ h_e, float* __restrict__ h_z,
        char* __restrict__ zfrag, char* __restrict__ efrag,
        float* __restrict__ out) {
    const int bid = blockIdx.x, tid = threadIdx.x;
    if (bid < 512) {                       // z frags [tile][zh0,zh1,zl0,zl1][lane] + norms
        __shared__ float red[2][2][16];
        int u = bid * 256 + tid;
        int l = u & 63, s = (u >> 6) & 1, t = u >> 7;   // t = bid*2 + (tid>>7)
        int n = t * 16 + (l & 15);
        int b = n >> 10, hw = n & 1023;
        int c0 = s * 32 + (l >> 4) * 8;
        const float* zp = z + (size_t)b * CHW_ + hw;
        float v[8];
        float ss = 0.f;
#pragma unroll
        for (int j = 0; j < 8; j++) {
            v[j] = zp[(c0 + j) * HW_];
            ss = fmaf(v[j], v[j], ss);
        }
        FragU hi, lo;
        split8(v, hi, lo);
        char* base = zfrag + (size_t)t * 4096 + l * 16;
        *(FragU*)(base + s * 1024) = hi;
        *(FragU*)(base + (2 + s) * 1024) = lo;
        ss += __shfl_xor(ss, 16);          // reduce over lgrp (lane bits 4,5)
        ss += __shfl_xor(ss, 32);
        if ((l >> 4) == 0) red[tid >> 7][s][l & 15] = ss;
        __syncthreads();
        if (tid < 32) {
            int tt = tid >> 4, r = tid & 15;
            h_z[(bid * 2 + tt) * 16 + r] = 0.5f * (red[tt][0][r] + red[tt][1][r]);
        }
    } else if (bid < 640) {                // e fragments, negated (4 KB/tile)
        int u = (bid - 512) * 256 + tid;
        int l = u & 63, s = (u >> 6) & 1, t = u >> 7;   // t 0..255
        int er = t * 16 + (l & 15);
        int c0 = s * 32 + (l >> 4) * 8;
        const float* ep = emb + (size_t)er * 64 + c0;
        float4 ea = *(const float4*)(ep);
        float4 eb = *(const float4*)(ep + 4);
        float v[8];
        v[0] = -ea.x; v[1] = -ea.y; v[2] = -ea.z; v[3] = -ea.w;
        v[4] = -eb.x; v[5] = -eb.y; v[6] = -eb.z; v[7] = -eb.w;
        FragU hi, lo;
        split8(v, hi, lo);
        char* base = efrag + (size_t)t * 4096 + l * 16;
        *(FragU*)(base + s * 1024) = hi;
        *(FragU*)(base + (2 + s) * 1024) = lo;
    } else {                               // h_e + loss init (16 blocks)
        int t = (bid - 640) * 256 + tid;   // 0..4095
        const float4* er = (const float4*)(emb + (size_t)t * 64);
        float s = 0.f;
#pragma unroll
        for (int k = 0; k < 16; k++) {
            float4 e4 = er[k];
            s = fmaf(e4.x, e4.x, s); s = fmaf(e4.y, e4.y, s);
            s = fmaf(e4.z, e4.z, s); s = fmaf(e4.w, e4.w, s);
        }
        h_e[t] = 0.5f * s;
        if (t == 0) out[LOSS_OFF] = 0.f;
    }
}

// ---- kernel 2: MFMA scan (R12 structure + XCD-aware mapping + med3) ------
// Grid 256; es = bid>>5 (8 e-splits), rb = bid&31 (32 row-groups): the 8
// blocks sharing a zfrag row-slice have bid%8 == rb%8 -> same XCD -> the
// slice is fetched into ONE L2 instead of eight.
// Block = 8 waves; wave: 4 row-tiles reg-resident x 512 e. e staged in 4
// chunks of 8 tiles into double-buffered LDS; per e-tile 5 ds_read -> 24 MFMA.
// acc = 0.5|z|^2 + 0.5|e|^2 - e.z (3-term split, err ~1e-5) = 0.5*d2 > 0.
// key = (f32 bits & ~0xFFF) | e_idx ; u32 min == lexicographic argmin.
__global__ __launch_bounds__(512) void vq_mfma(
        const char* __restrict__ zfrag, const char* __restrict__ efrag,
        const float* __restrict__ h_e, const float* __restrict__ h_z,
        unsigned* __restrict__ k1q, unsigned* __restrict__ k2q) {
    __shared__ char buf[2][32768];
    __shared__ __attribute__((aligned(16))) float sh_he[512];

    const int tid = threadIdx.x;
    const int lane = tid & 63;
    const int w = tid >> 6;
    const int lrow = lane & 15;
    const int lgrp = lane >> 4;
    const int es = blockIdx.x >> 5;   // e-split (512 e = 32 et)
    const int rb = blockIdx.x & 31;   // row-group (512 rows)
    const int e0t = es * 32;
    const int rt0 = rb * 32 + w * 4;  // wave's four row-tiles

    sh_he[tid] = h_e[es * 512 + tid];

    // stage chunk 0: wave w stages e-tile (e0t + w)
    {
        const char* src = efrag + (size_t)(e0t + w) * 4096 + lane * 16;
        char* dst = buf[0] + w * 4096;
#pragma unroll
        for (int i = 0; i < 4; i++) gload_lds16(src + i * 1024, dst + i * 1024);
    }

    // z frags resident: 4 row-tiles x (hi,lo) x 2 k-halves = 64 VGPR
    bf16x8 zh[4][2], zl[4][2];
    float hz[4];
#pragma unroll
    for (int r = 0; r < 4; r++) {
        const char* zb = zfrag + (size_t)(rt0 + r) * 4096 + lane * 16;
        zh[r][0] = *(const bf16x8*)(zb);
        zh[r][1] = *(const bf16x8*)(zb + 1024);
        zl[r][0] = *(const bf16x8*)(zb + 2048);
        zl[r][1] = *(const bf16x8*)(zb + 3072);
        hz[r] = h_z[(rt0 + r) * 16 + lrow];
    }

    unsigned s1k[4] = {~0u, ~0u, ~0u, ~0u};
    unsigned s2k[4] = {~0u, ~0u, ~0u, ~0u};

    __syncthreads();                  // chunk 0 staged (barrier drains vmcnt)
    for (int c = 0; c < 4; c++) {
        if (c < 3) {                  // issue next-chunk stage early
            const char* src = efrag + (size_t)(e0t + (c + 1) * 8 + w) * 4096
                              + lane * 16;
            char* dst = buf[(c + 1) & 1] + w * 4096;
#pragma unroll
            for (int i = 0; i < 4; i++) gload_lds16(src + i * 1024, dst + i * 1024);
        }

        const char* cb = buf[c & 1] + lane * 16;
#pragma unroll
        for (int j = 0; j < 8; j++) {
            const char* tb = cb + j * 4096;
            bf16x8 ah0 = *(const bf16x8*)(tb);
            bf16x8 ah1 = *(const bf16x8*)(tb + 1024);
            bf16x8 al0 = *(const bf16x8*)(tb + 2048);
            bf16x8 al1 = *(const bf16x8*)(tb + 3072);
            const int etl = c * 8 + j;                 // local et 0..31
            const f32x4 he = *(const f32x4*)&sh_he[etl * 16 + lgrp * 4];

            f32x4 a0 = he + hz[0], a1 = he + hz[1];
            f32x4 a2 = he + hz[2], a3 = he + hz[3];

            // term 1: eh . zh
            a0 = __builtin_amdgcn_mfma_f32_16x16x32_bf16(ah0, zh[0][0], a0, 0, 0, 0);
            a1 = __builtin_amdgcn_mfma_f32_16x16x32_bf16(ah0, zh[1][0], a1, 0, 0, 0);
            a2 = __builtin_amdgcn_mfma_f32_16x16x32_bf16(ah0, zh[2][0], a2, 0, 0, 0);
            a3 = __builtin_amdgcn_mfma_f32_16x16x32_bf16(ah0, zh[3][0], a3, 0, 0, 0);
            a0 = __builtin_amdgcn_mfma_f32_16x16x32_bf16(ah1, zh[0][1], a0, 0, 0, 0);
            a1 = __builtin_amdgcn_mfma_f32_16x16x32_bf16(ah1, zh[1][1], a1, 0, 0, 0);
            a2 = __builtin_amdgcn_mfma_f32_16x16x32_bf16(ah1, zh[2][1], a2, 0, 0, 0);
            a3 = __builtin_amdgcn_mfma_f32_16x16x32_bf16(ah1, zh[3][1], a3, 0, 0, 0);
            // term 2: el . zh
            a0 = __builtin_amdgcn_mfma_f32_16x16x32_bf16(al0, zh[0][0], a0, 0, 0, 0);
            a1 = __builtin_amdgcn_mfma_f32_16x16x32_bf16(al0, zh[1][0], a1, 0, 0, 0);
            a2 = __builtin_amdgcn_mfma_f32_16x16x32_bf16(al0, zh[2][0], a2, 0, 0, 0);
            a3 = __builtin_amdgcn_mfma_f32_16x16x32_bf16(al0, zh[3][0], a3, 0, 0, 0);
            a0 = __builtin_amdgcn_mfma_f32_16x16x32_bf16(al1, zh[0][1], a0, 0, 0, 0);
            a1 = __builtin_amdgcn_mfma_f32_16x16x32_bf16(al1, zh[1][1], a1, 0, 0, 0);
            a2 = __builtin_amdgcn_mfma_f32_16x16x32_bf16(al1, zh[2][1], a2, 0, 0, 0);
            a3 = __builtin_amdgcn_mfma_f32_16x16x32_bf16(al1, zh[3][1], a3, 0, 0, 0);
            // term 3: eh . zl
            a0 = __builtin_amdgcn_mfma_f32_16x16x32_bf16(ah0, zl[0][0], a0, 0, 0, 0);
            a1 = __builtin_amdgcn_mfma_f32_16x16x32_bf16(ah0, zl[1][0], a1, 0, 0, 0);
            a2 = __builtin_amdgcn_mfma_f32_16x16x32_bf16(ah0, zl[2][0], a2, 0, 0, 0);
            a3 = __builtin_amdgcn_mfma_f32_16x16x32_bf16(ah0, zl[3][0], a3, 0, 0, 0);
            a0 = __builtin_amdgcn_mfma_f32_16x16x32_bf16(ah1, zl[0][1], a0, 0, 0, 0);
            a1 = __builtin_amdgcn_mfma_f32_16x16x32_bf16(ah1, zl[1][1], a1, 0, 0, 0);
            a2 = __builtin_amdgcn_mfma_f32_16x16x32_bf16(ah1, zl[2][1], a2, 0, 0, 0);
            a3 = __builtin_amdgcn_mfma_f32_16x16x32_bf16(ah1, zl[3][1], a3, 0, 0, 0);

            const unsigned eb12 = (unsigned)(es * 512 + etl * 16 + lgrp * 4);
#pragma unroll
            for (int rr = 0; rr < 4; rr++) {
                top2_((__float_as_uint(a0[rr]) & 0xFFFFF000u) | (eb12 + rr), s1k[0], s2k[0]);
                top2_((__float_as_uint(a1[rr]) & 0xFFFFF000u) | (eb12 + rr), s1k[1], s2k[1]);
                top2_((__float_as_uint(a2[rr]) & 0xFFFFF000u) | (eb12 + rr), s1k[2], s2k[2]);
                top2_((__float_as_uint(a3[rr]) & 0xFFFFF000u) | (eb12 + rr), s1k[3], s2k[3]);
            }
        }
        __syncthreads();              // next chunk landed; buf[c&1] free
    }

    // merge across the 4 k-octet lane-groups (same z-row)
#pragma unroll
    for (int off = 16; off <= 32; off += 16) {
#pragma unroll
        for (int r = 0; r < 4; r++) {
            unsigned o1 = (unsigned)__shfl_xor((int)s1k[r], off);
            unsigned o2 = (unsigned)__shfl_xor((int)s2k[r], off);
            s2k[r] = umin_(umin_(s2k[r], o2), umax_(s1k[r], o1));
            s1k[r] = umin_(s1k[r], o1);
        }
    }

    if (lane < 16) {                  // plain stores; one owner per (row, es)
        const int base = es * 16384;
#pragma unroll
        for (int r = 0; r < 4; r++) {
            k1q[base + (rt0 + r) * 16 + lane] = s1k[r];
            k2q[base + (rt0 + r) * 16 + lane] = s2k[r];
        }
    }
}

// ---- kernel 3: merge 8 partials; outputs; fp64 duel for near-ties --------
// Plane-major: thread t -> row n = t & 16383, channel quarter q = t >> 14.
__global__ __launch_bounds__(256) void vq_final(
        const float* __restrict__ z, const float* __restrict__ emb,
        const unsigned* __restrict__ k1q, const unsigned* __restrict__ k2q,
        float* __restrict__ out) {
    int t = blockIdx.x * 256 + threadIdx.x;   // 256 blocks x 256 = 65536
    int n = t & 16383;
    int q = t >> 14;

    unsigned m = 0xFFFFFFFFu, s = 0xFFFFFFFFu;
#pragma unroll
    for (int i = 0; i < 8; i++) {
        unsigned a = k1q[i * 16384 + n];
        unsigned b = k2q[i * 16384 + n];
        unsigned hi = umax_(m, a);
        m = umin_(m, a);
        s = umin_(umin_(s, b), hi);
    }

    int idx = (int)(m & 0xFFFu);
    float s1 = __uint_as_float(m & 0xFFFFF000u);
    float s2 = __uint_as_float(s & 0xFFFFF000u);

    int b = n >> 10, hw = n & 1023;
    const float* zp = z + (size_t)b * CHW_ + hw;
    const int cq = q * 16;

    if (s2 - s1 < EPS_GAP) {                   // near-tie: exact fp64 duel
        int i2 = (int)(s & 0xFFFu);
        const float* ea = emb + (size_t)idx * 64;
        const float* eb = emb + (size_t)i2 * 64;
        double da = 0.0, db = 0.0;
#pragma unroll 8
        for (int c = 0; c < 64; c++) {
            double zv = (double)zp[c * HW_];
            double xa = (double)ea[c] - zv;
            double xb = (double)eb[c] - zv;
            da = fma(xa, xa, da);
            db = fma(xb, xb, db);
        }
        if (db < da || (db == da && i2 < idx)) idx = i2;
    }

    const float* er = emb + (size_t)idx * 64 + cq;
    float* zq = out + (size_t)b * CHW_ + hw;
    float lsum = 0.f;
#pragma unroll
    for (int j = 0; j < 16; j++) {
        float e = er[j];
        float d = e - zp[(cq + j) * HW_];
        zq[(cq + j) * HW_] = e;
        lsum = fmaf(d, d, lsum);
    }
    if (q == 0) out[IDX_OFF + n] = (float)idx;

#pragma unroll
    for (int off = 32; off; off >>= 1) lsum += __shfl_down(lsum, off);
    if ((threadIdx.x & 63) == 0) atomicAdd(&out[LOSS_OFF], lsum * LOSS_SCALE);
}

extern "C" void kernel_launch(void* const* d_in, const int* in_sizes, int n_in,
                              void* d_out, int out_size, void* d_ws, size_t ws_size,
                              hipStream_t stream) {
    const float* z   = (const float*)d_in[0];
    const float* emb = (const float*)d_in[1];
    float* out = (float*)d_out;
    char* ws = (char*)d_ws;

    char* efrag   = ws;                               // 1 MB
    char* zfrag   = ws + 1048576;                     // 4 MB
    float* h_e    = (float*)(ws + 5242880);           // 16 KB
    float* h_z    = (float*)(ws + 5259264);           // 64 KB
    unsigned* k1q = (unsigned*)(ws + 5324800);        // 512 KB (8 partials)
    unsigned* k2q = (unsigned*)(ws + 5849088);        // 512 KB

    vq_pre  <<<656, 256, 0, stream>>>(z, emb, h_e, h_z, zfrag, efrag, out);
    vq_mfma <<<256, 512, 0, stream>>>(zfrag, efrag, h_e, h_z, k1q, k2q);
    vq_final<<<256, 256, 0, stream>>>(z, emb, k1q, k2q, out);
}

// Round 17
// 51.546 us; speedup vs baseline: 2.0275x; 1.0002x over previous
//
#include <hip/hip_runtime.h>

typedef float f32x4 __attribute__((ext_vector_type(4)));
typedef short bf16x8 __attribute__((ext_vector_type(8)));

#define HW_ 1024
#define NE_ 4096
#define CHW_ 65536          // 64*1024
#define ZQ_SIZE 1048576
#define LOSS_OFF ZQ_SIZE
#define IDX_OFF (ZQ_SIZE + 1)
#define LOSS_SCALE (1.25f / 1048576.f)
#define EPS_GAP 0.1f        // 0.5*d2 scale; covers 12-bit trunc (~0.016) + split err (~1e-5)

union FragU { unsigned u[4]; bf16x8 v; };

__device__ __forceinline__ unsigned umin_(unsigned a, unsigned b) { return a < b ? a : b; }
__device__ __forceinline__ unsigned umax_(unsigned a, unsigned b) { return a > b ? a : b; }

// running top-2 update: s2 = median(key, s1, s2) ; s1 = min(s1, key)
__device__ __forceinline__ void top2_(unsigned key, unsigned& s1, unsigned& s2) {
    unsigned t;
    asm("v_med3_u32 %0, %1, %2, %3" : "=v"(t) : "v"(key), "v"(s1), "v"(s2));
    s2 = t;
    s1 = umin_(s1, key);
}

// split 8 f32 -> hi/lo bf16 fragments (truncation split; lo captures the tail)
__device__ __forceinline__ void split8(const float* v, FragU& hi, FragU& lo) {
#pragma unroll
    for (int p = 0; p < 4; p++) {
        float a = v[2 * p], b = v[2 * p + 1];
        unsigned ua = __float_as_uint(a), ub = __float_as_uint(b);
        hi.u[p] = (ua >> 16) | (ub & 0xFFFF0000u);
        float la = a - __uint_as_float(ua & 0xFFFF0000u);
        float lb = b - __uint_as_float(ub & 0xFFFF0000u);
        lo.u[p] = (__float_as_uint(la) >> 16) | (__float_as_uint(lb) & 0xFFFF0000u);
    }
}

__device__ __forceinline__ void gload_lds16(const void* g, void* l) {
    __builtin_amdgcn_global_load_lds(
        (const __attribute__((address_space(1))) unsigned*)g,
        (__attribute__((address_space(3))) unsigned*)l, 16, 0, 0);
}

// ---- kernel 1: efrag (negated, split) + h_e + loss init ------------------
__global__ __launch_bounds__(256) void vq_eprep(
        const float* __restrict__ emb, char* __restrict__ efrag,
        float* __restrict__ h_e, float* __restrict__ out) {
    const int bid = blockIdx.x, tid = threadIdx.x;
    if (bid < 128) {                       // e fragments, negated (4 KB/tile)
        int u = bid * 256 + tid;
        int l = u & 63, s = (u >> 6) & 1, t = u >> 7;   // t 0..255
        int er = t * 16 + (l & 15);
        int c0 = s * 32 + (l >> 4) * 8;
        const float* ep = emb + (size_t)er * 64 + c0;
        float4 ea = *(const float4*)(ep);
        float4 eb = *(const float4*)(ep + 4);
        float v[8];
        v[0] = -ea.x; v[1] = -ea.y; v[2] = -ea.z; v[3] = -ea.w;
        v[4] = -eb.x; v[5] = -eb.y; v[6] = -eb.z; v[7] = -eb.w;
        FragU hi, lo;
        split8(v, hi, lo);
        char* base = efrag + (size_t)t * 4096 + l * 16;
        *(FragU*)(base + s * 1024) = hi;
        *(FragU*)(base + (2 + s) * 1024) = lo;
    } else {                               // h_e (16 blocks) + loss init
        int t = (bid - 128) * 256 + tid;   // 0..4095
        const float4* er = (const float4*)(emb + (size_t)t * 64);
        float s = 0.f;
#pragma unroll
        for (int k = 0; k < 16; k++) {
            float4 e4 = er[k];
            s = fmaf(e4.x, e4.x, s); s = fmaf(e4.y, e4.y, s);
            s = fmaf(e4.z, e4.z, s); s = fmaf(e4.w, e4.w, s);
        }
        h_e[t] = 0.5f * s;
        if (t == 0) out[LOSS_OFF] = 0.f;
    }
}

// ---- kernel 2: MFMA scan, z-frags built in-kernel (no zfrag buffer) ------
// Grid 256; es = bid>>5 (8 e-splits), rb = bid&31 (32 row-groups): the 8
// blocks sharing a z row-slice have bid%8 == rb%8 -> same XCD -> slice
// fetched into ONE L2. Block = 8 waves; wave: 4 row-tiles reg-resident
// (built from z via split8; h_z via shfl) x 512 e. e staged in 4 chunks of
// 8 tiles into double-buffered LDS; per e-tile 5 ds_read -> 24 MFMA.
// acc = 0.5|z|^2 + 0.5|e|^2 - e.z (3-term split, err ~1e-5) = 0.5*d2 > 0.
// key = (f32 bits & ~0xFFF) | e_idx ; u32 min == lexicographic argmin.
__global__ __launch_bounds__(512) void vq_mfma(
        const float* __restrict__ z, const char* __restrict__ efrag,
        const float* __restrict__ h_e,
        unsigned* __restrict__ k1q, unsigned* __restrict__ k2q) {
    __shared__ char buf[2][32768];
    __shared__ __attribute__((aligned(16))) float sh_he[512];

    const int tid = threadIdx.x;
    const int lane = tid & 63;
    const int w = tid >> 6;
    const int lrow = lane & 15;
    const int lgrp = lane >> 4;
    const int es = blockIdx.x >> 5;   // e-split (512 e = 32 et)
    const int rb = blockIdx.x & 31;   // row-group (512 rows)
    const int e0t = es * 32;
    const int rt0 = rb * 32 + w * 4;  // wave's four row-tiles
    const int b = rb >> 1;            // batch image (block never crosses)

    sh_he[tid] = h_e[es * 512 + tid];

    // stage chunk 0: wave w stages e-tile (e0t + w)
    {
        const char* src = efrag + (size_t)(e0t + w) * 4096 + lane * 16;
        char* dst = buf[0] + w * 4096;
#pragma unroll
        for (int i = 0; i < 4; i++) gload_lds16(src + i * 1024, dst + i * 1024);
    }

    // build z-frags in registers (4 row-tiles x hi/lo x 2 k-halves) + norms
    bf16x8 zh[4][2], zl[4][2];
    float hz[4];
#pragma unroll
    for (int r = 0; r < 4; r++) {
        float ss = 0.f;
#pragma unroll
        for (int s = 0; s < 2; s++) {
            const int hw = ((rt0 + r) * 16 + lrow) & 1023;
            const int c0 = s * 32 + lgrp * 8;
            const float* zp = z + (size_t)b * CHW_ + hw;
            float v[8];
#pragma unroll
            for (int j = 0; j < 8; j++) {
                v[j] = zp[(c0 + j) * HW_];
                ss = fmaf(v[j], v[j], ss);
            }
            FragU hi, lo;
            split8(v, hi, lo);
            zh[r][s] = hi.v;
            zl[r][s] = lo.v;
        }
        ss += __shfl_xor(ss, 16);      // butterfly over lgrp (lane bits 4,5)
        ss += __shfl_xor(ss, 32);
        hz[r] = 0.5f * ss;
    }

    unsigned s1k[4] = {~0u, ~0u, ~0u, ~0u};
    unsigned s2k[4] = {~0u, ~0u, ~0u, ~0u};

    __syncthreads();                  // chunk 0 staged (barrier drains vmcnt)
    for (int c = 0; c < 4; c++) {
        if (c < 3) {                  // issue next-chunk stage early
            const char* src = efrag + (size_t)(e0t + (c + 1) * 8 + w) * 4096
                              + lane * 16;
            char* dst = buf[(c + 1) & 1] + w * 4096;
#pragma unroll
            for (int i = 0; i < 4; i++) gload_lds16(src + i * 1024, dst + i * 1024);
        }

        const char* cb = buf[c & 1] + lane * 16;
#pragma unroll
        for (int j = 0; j < 8; j++) {
            const char* tb = cb + j * 4096;
            bf16x8 ah0 = *(const bf16x8*)(tb);
            bf16x8 ah1 = *(const bf16x8*)(tb + 1024);
            bf16x8 al0 = *(const bf16x8*)(tb + 2048);
            bf16x8 al1 = *(const bf16x8*)(tb + 3072);
            const int etl = c * 8 + j;                 // local et 0..31
            const f32x4 he = *(const f32x4*)&sh_he[etl * 16 + lgrp * 4];

            f32x4 a0 = he + hz[0], a1 = he + hz[1];
            f32x4 a2 = he + hz[2], a3 = he + hz[3];

            // term 1: eh . zh
            a0 = __builtin_amdgcn_mfma_f32_16x16x32_bf16(ah0, zh[0][0], a0, 0, 0, 0);
            a1 = __builtin_amdgcn_mfma_f32_16x16x32_bf16(ah0, zh[1][0], a1, 0, 0, 0);
            a2 = __builtin_amdgcn_mfma_f32_16x16x32_bf16(ah0, zh[2][0], a2, 0, 0, 0);
            a3 = __builtin_amdgcn_mfma_f32_16x16x32_bf16(ah0, zh[3][0], a3, 0, 0, 0);
            a0 = __builtin_amdgcn_mfma_f32_16x16x32_bf16(ah1, zh[0][1], a0, 0, 0, 0);
            a1 = __builtin_amdgcn_mfma_f32_16x16x32_bf16(ah1, zh[1][1], a1, 0, 0, 0);
            a2 = __builtin_amdgcn_mfma_f32_16x16x32_bf16(ah1, zh[2][1], a2, 0, 0, 0);
            a3 = __builtin_amdgcn_mfma_f32_16x16x32_bf16(ah1, zh[3][1], a3, 0, 0, 0);
            // term 2: el . zh
            a0 = __builtin_amdgcn_mfma_f32_16x16x32_bf16(al0, zh[0][0], a0, 0, 0, 0);
            a1 = __builtin_amdgcn_mfma_f32_16x16x32_bf16(al0, zh[1][0], a1, 0, 0, 0);
            a2 = __builtin_amdgcn_mfma_f32_16x16x32_bf16(al0, zh[2][0], a2, 0, 0, 0);
            a3 = __builtin_amdgcn_mfma_f32_16x16x32_bf16(al0, zh[3][0], a3, 0, 0, 0);
            a0 = __builtin_amdgcn_mfma_f32_16x16x32_bf16(al1, zh[0][1], a0, 0, 0, 0);
            a1 = __builtin_amdgcn_mfma_f32_16x16x32_bf16(al1, zh[1][1], a1, 0, 0, 0);
            a2 = __builtin_amdgcn_mfma_f32_16x16x32_bf16(al1, zh[2][1], a2, 0, 0, 0);
            a3 = __builtin_amdgcn_mfma_f32_16x16x32_bf16(al1, zh[3][1], a3, 0, 0, 0);
            // term 3: eh . zl
            a0 = __builtin_amdgcn_mfma_f32_16x16x32_bf16(ah0, zl[0][0], a0, 0, 0, 0);
            a1 = __builtin_amdgcn_mfma_f32_16x16x32_bf16(ah0, zl[1][0], a1, 0, 0, 0);
            a2 = __builtin_amdgcn_mfma_f32_16x16x32_bf16(ah0, zl[2][0], a2, 0, 0, 0);
            a3 = __builtin_amdgcn_mfma_f32_16x16x32_bf16(ah0, zl[3][0], a3, 0, 0, 0);
            a0 = __builtin_amdgcn_mfma_f32_16x16x32_bf16(ah1, zl[0][1], a0, 0, 0, 0);
            a1 = __builtin_amdgcn_mfma_f32_16x16x32_bf16(ah1, zl[1][1], a1, 0, 0, 0);
            a2 = __builtin_amdgcn_mfma_f32_16x16x32_bf16(ah1, zl[2][1], a2, 0, 0, 0);
            a3 = __builtin_amdgcn_mfma_f32_16x16x32_bf16(ah1, zl[3][1], a3, 0, 0, 0);

            const unsigned eb12 = (unsigned)(es * 512 + etl * 16 + lgrp * 4);
#pragma unroll
            for (int rr = 0; rr < 4; rr++) {
                top2_((__float_as_uint(a0[rr]) & 0xFFFFF000u) | (eb12 + rr), s1k[0], s2k[0]);
                top2_((__float_as_uint(a1[rr]) & 0xFFFFF000u) | (eb12 + rr), s1k[1], s2k[1]);
                top2_((__float_as_uint(a2[rr]) & 0xFFFFF000u) | (eb12 + rr), s1k[2], s2k[2]);
                top2_((__float_as_uint(a3[rr]) & 0xFFFFF000u) | (eb12 + rr), s1k[3], s2k[3]);
            }
        }
        __syncthreads();              // next chunk landed; buf[c&1] free
    }

    // merge across the 4 k-octet lane-groups (same z-row)
#pragma unroll
    for (int off = 16; off <= 32; off += 16) {
#pragma unroll
        for (int r = 0; r < 4; r++) {
            unsigned o1 = (unsigned)__shfl_xor((int)s1k[r], off);
            unsigned o2 = (unsigned)__shfl_xor((int)s2k[r], off);
            s2k[r] = umin_(umin_(s2k[r], o2), umax_(s1k[r], o1));
            s1k[r] = umin_(s1k[r], o1);
        }
    }

    if (lane < 16) {                  // plain stores; one owner per (row, es)
        const int base = es * 16384;
#pragma unroll
        for (int r = 0; r < 4; r++) {
            k1q[base + (rt0 + r) * 16 + lane] = s1k[r];
            k2q[base + (rt0 + r) * 16 + lane] = s2k[r];
        }
    }
}

// ---- kernel 3: merge 8 partials; outputs; fp64 duel for near-ties --------
// Plane-major: thread t -> row n = t & 16383, channel quarter q = t >> 14.
__global__ __launch_bounds__(256) void vq_final(
        const float* __restrict__ z, const float* __restrict__ emb,
        const unsigned* __restrict__ k1q, const unsigned* __restrict__ k2q,
        float* __restrict__ out) {
    int t = blockIdx.x * 256 + threadIdx.x;   // 256 blocks x 256 = 65536
    int n = t & 16383;
    int q = t >> 14;

    unsigned m = 0xFFFFFFFFu, s = 0xFFFFFFFFu;
#pragma unroll
    for (int i = 0; i < 8; i++) {
        unsigned a = k1q[i * 16384 + n];
        unsigned b = k2q[i * 16384 + n];
        unsigned hi = umax_(m, a);
        m = umin_(m, a);
        s = umin_(umin_(s, b), hi);
    }

    int idx = (int)(m & 0xFFFu);
    float s1 = __uint_as_float(m & 0xFFFFF000u);
    float s2 = __uint_as_float(s & 0xFFFFF000u);

    int b = n >> 10, hw = n & 1023;
    const float* zp = z + (size_t)b * CHW_ + hw;
    const int cq = q * 16;

    if (s2 - s1 < EPS_GAP) {                   // near-tie: exact fp64 duel
        int i2 = (int)(s & 0xFFFu);
        const float* ea = emb + (size_t)idx * 64;
        const float* eb = emb + (size_t)i2 * 64;
        double da = 0.0, db = 0.0;
#pragma unroll 8
        for (int c = 0; c < 64; c++) {
            double zv = (double)zp[c * HW_];
            double xa = (double)ea[c] - zv;
            double xb = (double)eb[c] - zv;
            da = fma(xa, xa, da);
            db = fma(xb, xb, db);
        }
        if (db < da || (db == da && i2 < idx)) idx = i2;
    }

    const float* er = emb + (size_t)idx * 64 + cq;
    float* zq = out + (size_t)b * CHW_ + hw;
    float lsum = 0.f;
#pragma unroll
    for (int j = 0; j < 16; j++) {
        float e = er[j];
        float d = e - zp[(cq + j) * HW_];
        zq[(cq + j) * HW_] = e;
        lsum = fmaf(d, d, lsum);
    }
    if (q == 0) out[IDX_OFF + n] = (float)idx;

#pragma unroll
    for (int off = 32; off; off >>= 1) lsum += __shfl_down(lsum, off);
    if ((threadIdx.x & 63) == 0) atomicAdd(&out[LOSS_OFF], lsum * LOSS_SCALE);
}

extern "C" void kernel_launch(void* const* d_in, const int* in_sizes, int n_in,
                              void* d_out, int out_size, void* d_ws, size_t ws_size,
                              hipStream_t stream) {
    const float* z   = (const float*)d_in[0];
    const float* emb = (const float*)d_in[1];
    float* out = (float*)d_out;
    char* ws = (char*)d_ws;

    char* efrag   = ws;                               // 1 MB
    float* h_e    = (float*)(ws + 1048576);           // 16 KB
    unsigned* k1q = (unsigned*)(ws + 1065024);        // 512 KB (8 partials)
    unsigned* k2q = (unsigned*)(ws + 1589312);        // 512 KB

    vq_eprep<<<144, 256, 0, stream>>>(emb, efrag, h_e, out);
    vq_mfma <<<256, 512, 0, stream>>>(z, efrag, h_e, k1q, k2q);
    vq_final<<<256, 256, 0, stream>>>(z, emb, k1q, k2q, out);
}